// Round 15
// baseline (262.540 us; speedup 1.0000x reference)
//
#include <hip/hip_runtime.h>
#include <hip/hip_fp16.h>
#include <math.h>

#define NN 4096
#define CC 256

typedef __attribute__((ext_vector_type(8))) short bf16x8;
typedef __attribute__((ext_vector_type(8))) _Float16 f16x8;
typedef __attribute__((ext_vector_type(4))) float f32x4;
typedef __attribute__((ext_vector_type(16))) float f32x16;
typedef __attribute__((ext_vector_type(8))) unsigned short u16x8;
typedef __attribute__((ext_vector_type(4))) unsigned short u16x4;
typedef __attribute__((ext_vector_type(4))) unsigned int u32x4;

__device__ inline unsigned short f2bf(float f) {
  unsigned u = __float_as_uint(f);
  return (unsigned short)((u + 0x7FFFu + ((u >> 16) & 1u)) >> 16);
}
__device__ inline float bf2f(unsigned short u) {
  return __uint_as_float(((unsigned)u) << 16);
}
__device__ inline unsigned short f2h(float f) {
  __half h = __float2half(f);
  return static_cast<__half_raw>(h).x;
}

// async global->LDS, 16B per lane; dest = wave-uniform base + lane*16
__device__ inline void gload16(const void* g, void* l) {
  __builtin_amdgcn_global_load_lds(
      (const __attribute__((address_space(1))) void*)g,
      (__attribute__((address_space(3))) void*)l, 16, 0, 0);
}

// ---------------------------------------------------------------------------
// prep_w: w [co][ci][3][3] f32 -> wT2 [4][9][co][ci] bf16 (B^T per shift).
// ---------------------------------------------------------------------------
__global__ __launch_bounds__(256) void prep_w(
    const float* __restrict__ w0, const float* __restrict__ w1,
    const float* __restrict__ w2, const float* __restrict__ w3,
    unsigned short* __restrict__ wT2, unsigned short* __restrict__ zp)
{
  int bx = blockIdx.x;
  int widx = bx >> 8;
  const float* src = (widx == 0) ? w0 : (widx == 1) ? w1 : (widx == 2) ? w2 : w3;
  int p = ((bx & 255) << 8) + threadIdx.x;          // p = co*256 + ci
  unsigned short* dst = wT2 + (size_t)widx * 589824;
  const float* s9 = src + (size_t)p * 9;
#pragma unroll
  for (int s = 0; s < 9; ++s) dst[(size_t)s * 65536 + p] = f2bf(s9[s]);
  if (bx == 0 && threadIdx.x < 128) zp[threadIdx.x] = 0;
}

// ---------------------------------------------------------------------------
// prep_x: x [B][C][H][W] f32 -> xT [B][N][C] bf16.
// ---------------------------------------------------------------------------
__global__ __launch_bounds__(256) void prep_x(
    const float* __restrict__ x, unsigned short* __restrict__ xT)
{
  __shared__ unsigned short T[64][72];
  int tid = threadIdx.x, bx = blockIdx.x;
  int b = bx >> 8, c0 = ((bx >> 6) & 3) * 64, n0 = (bx & 63) * 64;
#pragma unroll
  for (int it = 0; it < 16; ++it) {
    int c_l = (tid >> 6) + it * 4;
    int n_l = tid & 63;
    T[n_l][c_l] = f2bf(x[((size_t)(b * 256 + c0 + c_l)) * 4096 + n0 + n_l]);
  }
  __syncthreads();
#pragma unroll
  for (int it = 0; it < 8; ++it) {
    int n_l = (tid >> 5) + it * 8;
    int cp = (tid & 31) * 2;
    unsigned v = (unsigned)T[n_l][cp] | ((unsigned)T[n_l][cp + 1] << 16);
    *(unsigned*)&xT[((size_t)(b * 4096 + n0 + n_l)) * 256 + c0 + cp] = v;
  }
}

// ---------------------------------------------------------------------------
// conv3x_k: the 3 QKV convs as ONE launch, grid (512, 3).  blockIdx.y picks
// weights/bias/output.  Tile 128(M) x 64(N), 9 accumulated shift-GEMMs,
// bf16 MFMA 16x16x32, XCD-swizzled blockIdx.x (512 = 8 XCD x 64).
// y=0 -> qT fp16 [B][N][C]; y=1 -> kT; y=2 -> vTc fp16 [B][C][N].
// ---------------------------------------------------------------------------
__global__ __launch_bounds__(256) void conv3x_k(
    const unsigned short* __restrict__ A,
    const unsigned short* __restrict__ wT2,     // [4][9][256][256]
    const float* __restrict__ bq, const float* __restrict__ bk,
    const float* __restrict__ bvv,
    unsigned short* __restrict__ qT, unsigned short* __restrict__ kT,
    unsigned short* __restrict__ vTc,
    const unsigned short* __restrict__ zp)
{
  __shared__ unsigned short As[2][128 * 64];   // 2 x 16KB
  __shared__ unsigned short Bs[2][64 * 64];    // 2 x 8KB

  const int by = blockIdx.y;
  const unsigned short* W = wT2 + (size_t)by * 589824;
  const float* bias = (by == 0) ? bq : (by == 1) ? bk : bvv;
  unsigned short* outp = (by == 0) ? qT : (by == 1) ? kT : vTc;
  const int mode2 = (by == 2);

  const int bx = blockIdx.x;
  const int bxs = ((bx & 7) << 6) + (bx >> 3);   // XCD-contiguous swizzle
  const int tid = threadIdx.x;
  const int lane = tid & 63;
  const int w = tid >> 6;
  const int wr = w >> 1, wc = w & 1;
  const int nt = bxs & 3;
  const int mt = bxs >> 2;
  const int m0 = mt * 128;
  const int co0 = nt * 64;

  const int aslot = (lane & 7) ^ (lane >> 3);
  int gmj[4], yj[4], xj[4];
#pragma unroll
  for (int j = 0; j < 4; ++j) {
    int row = w * 32 + j * 8 + (lane >> 3);
    int gm = m0 + row;
    gmj[j] = gm;
    int n = gm & (NN - 1);
    yj[j] = n >> 6;
    xj[j] = n & 63;
  }
  int browj[2];
#pragma unroll
  for (int j = 0; j < 2; ++j)
    browj[j] = co0 + w * 16 + j * 8 + (lane >> 3);

  f32x4 acc[4][2];
#pragma unroll
  for (int mi = 0; mi < 4; ++mi)
#pragma unroll
    for (int ni = 0; ni < 2; ++ni) acc[mi][ni] = (f32x4){0.f, 0.f, 0.f, 0.f};

  auto stage = [&](int step, int sb) {
    int s = step >> 2, t = step & 3;
    int dy = s / 3 - 1, dx = s - (s / 3) * 3 - 1;
    const unsigned short* abase = A + t * 64 + aslot * 8;
    const unsigned short* wbase = W + ((size_t)s << 16) + t * 64 + aslot * 8;
#pragma unroll
    for (int j = 0; j < 4; ++j) {
      int yy = yj[j] + dy, xx = xj[j] + dx;
      bool valid = ((unsigned)yy < 64u) && ((unsigned)xx < 64u);
      const void* ga = valid
          ? (const void*)(abase + (size_t)(gmj[j] + dy * 64 + dx) * 256)
          : (const void*)zp;
      gload16(ga, (void*)&As[sb][(w * 4 + j) * 512]);
    }
#pragma unroll
    for (int j = 0; j < 2; ++j) {
      const void* gb = (const void*)(wbase + (size_t)browj[j] * 256);
      gload16(gb, (void*)&Bs[sb][(w * 2 + j) * 512]);
    }
  };

  const int r = lane & 15;
  const int klane = lane >> 4;
  const int rs = r & 7;

  int buf = 0;
  stage(0, 0);
  __syncthreads();
  for (int step = 0; step < 36; ++step) {
    if (step + 1 < 36) stage(step + 1, buf ^ 1);
    const unsigned short* as = As[buf];
    const unsigned short* bs = Bs[buf];
#pragma unroll
    for (int kk = 0; kk < 2; ++kk) {
      int slot = (kk * 4 + klane) ^ rs;
      bf16x8 a[4], bfr[2];
#pragma unroll
      for (int mi = 0; mi < 4; ++mi)
        a[mi] = *(const bf16x8*)&as[(wr * 64 + mi * 16 + r) * 64 + slot * 8];
#pragma unroll
      for (int ni = 0; ni < 2; ++ni)
        bfr[ni] = *(const bf16x8*)&bs[(wc * 32 + ni * 16 + r) * 64 + slot * 8];
#pragma unroll
      for (int mi = 0; mi < 4; ++mi)
#pragma unroll
        for (int ni = 0; ni < 2; ++ni)
          acc[mi][ni] = __builtin_amdgcn_mfma_f32_16x16x32_bf16(
              a[mi], bfr[ni], acc[mi][ni], 0, 0, 0);
    }
    __syncthreads();
    buf ^= 1;
  }

  const int r4 = lane >> 4;
  const int colb = lane & 15;
  if (!mode2) {
#pragma unroll
    for (int ni = 0; ni < 2; ++ni) {
      int co = co0 + wc * 32 + ni * 16 + colb;
      float bv = bias[co];
#pragma unroll
      for (int mi = 0; mi < 4; ++mi) {
        int gm0 = m0 + wr * 64 + mi * 16 + r4 * 4;
#pragma unroll
        for (int rr = 0; rr < 4; ++rr) {
          float v = fmaxf(acc[mi][ni][rr] + bv, 0.f);
          outp[(size_t)(gm0 + rr) * 256 + co] = f2h(v);
        }
      }
    }
  } else {
#pragma unroll
    for (int ni = 0; ni < 2; ++ni) {
      int co = co0 + wc * 32 + ni * 16 + colb;
      float bv = bias[co];
#pragma unroll
      for (int mi = 0; mi < 4; ++mi) {
        int gm0 = m0 + wr * 64 + mi * 16 + r4 * 4;
#pragma unroll
        for (int rr = 0; rr < 4; ++rr) {
          float v = fmaxf(acc[mi][ni][rr] + bv, 0.f);
          int gm = gm0 + rr;
          int b = gm >> 12, n = gm & (NN - 1);
          outp[((size_t)(b * 256 + co)) * 4096 + n] = f2h(v);
        }
      }
    }
  }
}

// ---------------------------------------------------------------------------
// conv_mfma: final 3x3 conv, tile 128x64, XCD-swizzled; f32 [B][C][H][W] out.
// ---------------------------------------------------------------------------
__global__ __launch_bounds__(256) void conv_mfma(
    const unsigned short* __restrict__ A,
    const unsigned short* __restrict__ W,
    const float* __restrict__ bias,
    float* __restrict__ out,
    const unsigned short* __restrict__ zp)
{
  __shared__ unsigned short As[2][128 * 64];
  __shared__ unsigned short Bs[2][64 * 64];

  const int bx = blockIdx.x;
  const int bxs = ((bx & 7) << 6) + (bx >> 3);
  const int tid = threadIdx.x;
  const int lane = tid & 63;
  const int w = tid >> 6;
  const int wr = w >> 1, wc = w & 1;
  const int nt = bxs & 3;
  const int mt = bxs >> 2;
  const int m0 = mt * 128;
  const int co0 = nt * 64;

  const int aslot = (lane & 7) ^ (lane >> 3);
  int gmj[4], yj[4], xj[4];
#pragma unroll
  for (int j = 0; j < 4; ++j) {
    int row = w * 32 + j * 8 + (lane >> 3);
    int gm = m0 + row;
    gmj[j] = gm;
    int n = gm & (NN - 1);
    yj[j] = n >> 6;
    xj[j] = n & 63;
  }
  int browj[2];
#pragma unroll
  for (int j = 0; j < 2; ++j)
    browj[j] = co0 + w * 16 + j * 8 + (lane >> 3);

  f32x4 acc[4][2];
#pragma unroll
  for (int mi = 0; mi < 4; ++mi)
#pragma unroll
    for (int ni = 0; ni < 2; ++ni) acc[mi][ni] = (f32x4){0.f, 0.f, 0.f, 0.f};

  auto stage = [&](int step, int sb) {
    int s = step >> 2, t = step & 3;
    int dy = s / 3 - 1, dx = s - (s / 3) * 3 - 1;
    const unsigned short* abase = A + t * 64 + aslot * 8;
    const unsigned short* wbase = W + ((size_t)s << 16) + t * 64 + aslot * 8;
#pragma unroll
    for (int j = 0; j < 4; ++j) {
      int yy = yj[j] + dy, xx = xj[j] + dx;
      bool valid = ((unsigned)yy < 64u) && ((unsigned)xx < 64u);
      const void* ga = valid
          ? (const void*)(abase + (size_t)(gmj[j] + dy * 64 + dx) * 256)
          : (const void*)zp;
      gload16(ga, (void*)&As[sb][(w * 4 + j) * 512]);
    }
#pragma unroll
    for (int j = 0; j < 2; ++j) {
      const void* gb = (const void*)(wbase + (size_t)browj[j] * 256);
      gload16(gb, (void*)&Bs[sb][(w * 2 + j) * 512]);
    }
  };

  const int r = lane & 15;
  const int klane = lane >> 4;
  const int rs = r & 7;

  int buf = 0;
  stage(0, 0);
  __syncthreads();
  for (int step = 0; step < 36; ++step) {
    if (step + 1 < 36) stage(step + 1, buf ^ 1);
    const unsigned short* as = As[buf];
    const unsigned short* bs = Bs[buf];
#pragma unroll
    for (int kk = 0; kk < 2; ++kk) {
      int slot = (kk * 4 + klane) ^ rs;
      bf16x8 a[4], bfr[2];
#pragma unroll
      for (int mi = 0; mi < 4; ++mi)
        a[mi] = *(const bf16x8*)&as[(wr * 64 + mi * 16 + r) * 64 + slot * 8];
#pragma unroll
      for (int ni = 0; ni < 2; ++ni)
        bfr[ni] = *(const bf16x8*)&bs[(wc * 32 + ni * 16 + r) * 64 + slot * 8];
#pragma unroll
      for (int mi = 0; mi < 4; ++mi)
#pragma unroll
        for (int ni = 0; ni < 2; ++ni)
          acc[mi][ni] = __builtin_amdgcn_mfma_f32_16x16x32_bf16(
              a[mi], bfr[ni], acc[mi][ni], 0, 0, 0);
    }
    __syncthreads();
    buf ^= 1;
  }

  const int r4 = lane >> 4;
  const int colb = lane & 15;
#pragma unroll
  for (int ni = 0; ni < 2; ++ni) {
    int co = co0 + wc * 32 + ni * 16 + colb;
    float bv = bias[co];
#pragma unroll
    for (int mi = 0; mi < 4; ++mi) {
      int gm0 = m0 + wr * 64 + mi * 16 + r4 * 4;
#pragma unroll
      for (int rr = 0; rr < 4; ++rr) {
        float v = fmaxf(acc[mi][ni][rr] + bv, 0.f);
        int gm = gm0 + rr;
        int b = gm >> 12, n = gm & (NN - 1);
        out[((size_t)(b * 256 + co)) * 4096 + n] = v;
      }
    }
  }
}

// ---------------------------------------------------------------------------
// MFMA flash attention v10: 32KB LDS (K single-buffered 16KB + V
// single-buffered 16KB) -> 4 blocks/CU under the ~128KB-usable residency
// cap (r7/r13/r14: 64KB->2, 48KB->2 even with grid supply).  K(t+1) is
// prefetched into REGISTERS (4 x dwordx4/thread, T14) and ds_written to Ks
// between the two existing __syncthreads:
//   stageV(t) [gload_lds] ; load K(t+1)->regs ; QK^T on Ks ; softmax ; pack
//   __syncthreads (beta: V landed; all QK^T reads of Ks done)
//   PV on Vts ; ds_write K(t+1)->Ks
//   __syncthreads (alpha: PV done -> Vts free; K writes visible)
// Still 2 barriers/chunk, all __syncthreads (proper fences; no r11 race
// class).  4-way key split (grid 1024 = 8 XCD x 128) supplies 4 blocks/CU.
// Emits unnormalized partial O^T (bf16) + (m, l) per query.
// ---------------------------------------------------------------------------
__global__ __launch_bounds__(256, 2) void attn_k(
    const unsigned short* __restrict__ qT, const unsigned short* __restrict__ kT,
    const unsigned short* __restrict__ vTc,
    unsigned short* __restrict__ pA, unsigned short* __restrict__ pB,
    unsigned short* __restrict__ pC, unsigned short* __restrict__ pD,
    float2* __restrict__ pml)
{
  __shared__ unsigned short Ks[32 * 256];    // 16KB, [key][c], swizzled
  __shared__ unsigned short Vts[256 * 32];   // 16KB, [c][key], swizzled

  const int tid = threadIdx.x;
  const int lane = tid & 63;
  const int w = tid >> 6;
  const int wq = w >> 1, wc = w & 1;
  const int hi = lane >> 5;
  const int la = lane & 31;
  const int a7 = la & 7;
  const int bx = blockIdx.x;
  const int bxs = ((bx & 7) << 7) + (bx >> 3);   // 1024 = 8 XCD x 128
  const int quarter = bxs >> 8;
  const int b = (bxs >> 6) & 3;
  const int q0 = (bxs & 63) << 6;
  const int kbase = quarter << 10;

  // ---- Q as B-fragments: qf[ks] = Q[q0+32wq+la][16ks+8hi .. +8] ----
  f16x8 qf[16];
  {
    const unsigned short* qp =
        qT + ((size_t)(b * NN) + q0 + 32 * wq + la) * CC + 8 * hi;
#pragma unroll
    for (int ks = 0; ks < 16; ++ks)
      qf[ks] = *(const f16x8*)(qp + ks * 16);
  }

  const unsigned short* kTb = kT + (size_t)b * NN * CC;
  const unsigned short* vTb = vTc + (size_t)b * CC * NN;

  // K reg-staging geometry: issue i covers rows 8w+2i + (lane>>5), slot lane&31
  const int krow_l = lane >> 5;
  const int kslot = lane & 31;
  int krow[4];
  const unsigned short* ksrc[4];
  unsigned short* kdst[4];
#pragma unroll
  for (int i = 0; i < 4; ++i) {
    krow[i] = 8 * w + 2 * i + krow_l;
    ksrc[i] = kTb + ((kslot ^ (krow[i] & 7)) << 3);   // + (k0+row)*CC at use
    kdst[i] = &Ks[krow[i] * 256 + kslot * 8];
  }

  auto loadKreg = [&](int t, u16x8* kreg) {
    int k0 = kbase + (t << 5);
#pragma unroll
    for (int i = 0; i < 4; ++i)
      kreg[i] = *(const u16x8*)(ksrc[i] + (size_t)(k0 + krow[i]) * CC);
  };
  auto stageV = [&](int t) {
    int k0 = kbase + (t << 5);
    int c_l = lane >> 2;
    int sp = lane & 3;
#pragma unroll
    for (int i = 0; i < 4; ++i) {
      int c = 64 * w + 16 * i + c_l;
      const void* src = (const void*)(vTb + (size_t)c * NN + k0 +
                                      ((sp ^ ((c >> 2) & 3)) << 3));
      gload16(src, (void*)&Vts[(64 * w + 16 * i) * 32]);
    }
  };

  float mprev = -INFINITY, lsum = 0.f;
  f32x16 O[4];
#pragma unroll
  for (int nc = 0; nc < 4; ++nc)
#pragma unroll
    for (int rr = 0; rr < 16; ++rr) O[nc][rr] = 0.f;

  // ---- prologue: K(0) -> regs -> LDS ----
  {
    u16x8 k0reg[4];
    loadKreg(0, k0reg);
#pragma unroll
    for (int i = 0; i < 4; ++i) *(u16x8*)kdst[i] = k0reg[i];
  }
  __syncthreads();

  for (int t = 0; t < 32; ++t) {
    stageV(t);                      // gload_lds -> Vts (free since alpha(t-1))
    u16x8 kreg[4];
    if (t + 1 < 32) loadKreg(t + 1, kreg);

    // ---- QK^T (swapped): S^T[32 keys][32 q] ----
    f32x16 S0;
#pragma unroll
    for (int rr = 0; rr < 16; ++rr) S0[rr] = 0.f;
    __builtin_amdgcn_s_setprio(1);
#pragma unroll
    for (int ks = 0; ks < 16; ++ks) {
      f16x8 a0 = *(const f16x8*)&Ks[la * 256 + ((((ks << 1) + hi) ^ a7) << 3)];
      S0 = __builtin_amdgcn_mfma_f32_32x32x16_f16(a0, qf[ks], S0, 0, 0, 0);
    }
    __builtin_amdgcn_s_setprio(0);

    // ---- online softmax, defer-rescale (THR=8) ----
    float mloc = S0[0];
#pragma unroll
    for (int rr = 1; rr < 16; ++rr) mloc = fmaxf(mloc, S0[rr]);
    {
      auto sw = __builtin_amdgcn_permlane32_swap(
          __float_as_uint(mloc), __float_as_uint(mloc), false, false);
      mloc = fmaxf(__uint_as_float(sw[0]), __uint_as_float(sw[1]));
    }
    if (!__all(mloc <= mprev + 8.f)) {
      float mnew = fmaxf(mprev, mloc);
      float sc = __expf(mprev - mnew);   // exp(-inf)=0 on first chunk
      lsum *= sc;
#pragma unroll
      for (int nc = 0; nc < 4; ++nc)
#pragma unroll
        for (int rr = 0; rr < 16; ++rr) O[nc][rr] *= sc;
      mprev = mnew;
    }
    float rsm = 0.f;
#pragma unroll
    for (int rr = 0; rr < 16; ++rr) {
      S0[rr] = __expf(S0[rr] - mprev);
      rsm += S0[rr];
    }
    {
      auto sw = __builtin_amdgcn_permlane32_swap(
          __float_as_uint(rsm), __float_as_uint(rsm), false, false);
      rsm = __uint_as_float(sw[0]) + __uint_as_float(sw[1]);
    }
    lsum += rsm;

    // ---- pack P to fp16 A-row-fragments (cvt_pkrtz + permlane32_swap) ----
    f16x8 pf[2];
#pragma unroll
    for (int kk = 0; kk < 2; ++kk) {
      const int r0 = kk * 8;
      unsigned w0 = __builtin_bit_cast(unsigned,
          __builtin_amdgcn_cvt_pkrtz(S0[r0 + 0], S0[r0 + 1]));
      unsigned w1 = __builtin_bit_cast(unsigned,
          __builtin_amdgcn_cvt_pkrtz(S0[r0 + 2], S0[r0 + 3]));
      unsigned w2 = __builtin_bit_cast(unsigned,
          __builtin_amdgcn_cvt_pkrtz(S0[r0 + 4], S0[r0 + 5]));
      unsigned w3 = __builtin_bit_cast(unsigned,
          __builtin_amdgcn_cvt_pkrtz(S0[r0 + 6], S0[r0 + 7]));
      auto sA = __builtin_amdgcn_permlane32_swap(w0, w2, false, false);
      auto sB = __builtin_amdgcn_permlane32_swap(w1, w3, false, false);
      u32x4 fw;
      fw[0] = sA[0]; fw[1] = sB[0]; fw[2] = sA[1]; fw[3] = sB[1];
      pf[kk] = __builtin_bit_cast(f16x8, fw);
    }

    __syncthreads();   // beta: V(t) landed; all QK^T reads of Ks complete

    // ---- PV: O^T[c][q] += Vt-frag x P-frag ----
    __builtin_amdgcn_s_setprio(1);
#pragma unroll
    for (int kk = 0; kk < 2; ++kk) {
#pragma unroll
      for (int nc = 0; nc < 4; ++nc) {
        int c = 128 * wc + 32 * nc + la;
        f16x8 vf = *(const f16x8*)&Vts[c * 32 +
                                       ((((kk << 1) + hi) ^ ((c >> 2) & 3)) << 3)];
        O[nc] = __builtin_amdgcn_mfma_f32_32x32x16_f16(vf, pf[kk], O[nc], 0, 0, 0);
      }
    }
    __builtin_amdgcn_s_setprio(0);

    // ---- publish K(t+1) into Ks (safe: all Ks reads done at beta) ----
    if (t + 1 < 32) {
#pragma unroll
      for (int i = 0; i < 4; ++i) *(u16x8*)kdst[i] = kreg[i];
    }

    __syncthreads();   // alpha: PV done -> Vts free; K(t+1) visible
  }

  // ---- epilogue: unnormalized partial O^T (bf16) + (m,l) ----
  {
    int n = q0 + 32 * wq + la;
    unsigned short* pOq = (quarter == 0) ? pA : (quarter == 1) ? pB
                        : (quarter == 2) ? pC : pD;
    unsigned short* dst = pOq + ((size_t)b * NN + n) * CC;
#pragma unroll
    for (int nc = 0; nc < 4; ++nc) {
#pragma unroll
      for (int tq = 0; tq < 4; ++tq) {
        int c0 = 128 * wc + 32 * nc + 8 * tq + 4 * hi;
        u16x4 pk;
        pk[0] = f2bf(O[nc][4 * tq + 0]);
        pk[1] = f2bf(O[nc][4 * tq + 1]);
        pk[2] = f2bf(O[nc][4 * tq + 2]);
        pk[3] = f2bf(O[nc][4 * tq + 3]);
        *(u16x4*)&dst[c0] = pk;
      }
    }
    if (wc == 0 && hi == 0)
      pml[((size_t)quarter * 4 + b) * NN + n] = make_float2(mprev, lsum);
  }
}

// ---------------------------------------------------------------------------
// combine_k: merge 4 key-quarter partials -> ctx bf16 [B][N][C] (x2).
// NOTE: p1 aliases ctx (same index read-then-write per element).
// ---------------------------------------------------------------------------
__global__ __launch_bounds__(256) void combine_k(
    const unsigned short* __restrict__ p0, const unsigned short* __restrict__ p1,
    const unsigned short* __restrict__ p2, const unsigned short* __restrict__ p3,
    const float2* __restrict__ pml, unsigned short* __restrict__ ctx)
{
  int bx = blockIdx.x;                       // 512 blocks
  int b = bx >> 7;
  int q = ((bx & 127) << 5) + (threadIdx.x >> 3);
  int c0 = (threadIdx.x & 7) << 5;
  float2 ml0 = pml[(size_t)(0 * 4 + b) * NN + q];
  float2 ml1 = pml[(size_t)(1 * 4 + b) * NN + q];
  float2 ml2 = pml[(size_t)(2 * 4 + b) * NN + q];
  float2 ml3 = pml[(size_t)(3 * 4 + b) * NN + q];
  float m = fmaxf(fmaxf(ml0.x, ml1.x), fmaxf(ml2.x, ml3.x));
  float w0 = __expf(ml0.x - m), w1 = __expf(ml1.x - m);
  float w2 = __expf(ml2.x - m), w3 = __expf(ml3.x - m);
  float inv = 2.f / (ml0.y * w0 + ml1.y * w1 + ml2.y * w2 + ml3.y * w3);
  size_t base = ((size_t)b * NN + q) * CC + c0;
#pragma unroll
  for (int j = 0; j < 4; ++j) {
    u16x8 a0 = *(const u16x8*)(p0 + base + j * 8);
    u16x8 a1 = *(const u16x8*)(p1 + base + j * 8);
    u16x8 a2 = *(const u16x8*)(p2 + base + j * 8);
    u16x8 a3 = *(const u16x8*)(p3 + base + j * 8);
    u16x8 o;
#pragma unroll
    for (int e = 0; e < 8; ++e)
      o[e] = f2bf((bf2f(a0[e]) * w0 + bf2f(a1[e]) * w1 +
                   bf2f(a2[e]) * w2 + bf2f(a3[e]) * w3) * inv);
    *(u16x8*)(ctx + base + j * 8) = o;
  }
}

extern "C" void kernel_launch(void* const* d_in, const int* in_sizes, int n_in,
                              void* d_out, int out_size, void* d_ws, size_t ws_size,
                              hipStream_t stream) {
  const float* x  = (const float*)d_in[0];
  const float* wq = (const float*)d_in[1];
  const float* bq = (const float*)d_in[2];
  const float* wk = (const float*)d_in[3];
  const float* bk = (const float*)d_in[4];
  const float* wv = (const float*)d_in[5];
  const float* bv = (const float*)d_in[6];
  const float* wo = (const float*)d_in[7];
  const float* bo = (const float*)d_in[8];

  char* ws = (char*)d_ws;
  unsigned short* xT  = (unsigned short*)(ws);              // bf16 [B][N][C]; later pO q0
  unsigned short* wT2 = (unsigned short*)(ws + 8388608);    // bf16 [4][9][co][ci]
  unsigned short* qT  = (unsigned short*)(ws + 13107200);   // fp16 [B][N][C]
  unsigned short* kT  = (unsigned short*)(ws + 21495808);   // fp16 [B][N][C]
  unsigned short* vTc = (unsigned short*)(ws + 29884416);   // fp16 [B][C][N]
  unsigned short* ctx = (unsigned short*)(ws + 38273024);   // bf16 [B][N][C]; also pO q1
  unsigned short* zp  = (unsigned short*)(ws + 46661632);   // 512 B zeros
  unsigned short* pO2 = (unsigned short*)(ws + 46662144);   // bf16 [B][N][C]
  unsigned short* pO3 = (unsigned short*)(ws + 55050752);   // bf16 [B][N][C]
  float2*         pml = (float2*)(ws + 63439360);           // f32x2 [4][B][N] 512KB

  prep_w<<<dim3(1024), 256, 0, stream>>>(wq, wk, wv, wo, wT2, zp);
  prep_x<<<dim3(1024), 256, 0, stream>>>(x, xT);
  conv3x_k<<<dim3(512, 3), 256, 0, stream>>>(xT, wT2, bq, bk, bv, qT, kT, vTc, zp);
  attn_k<<<dim3(1024), 256, 0, stream>>>(qT, kT, vTc, xT, ctx, pO2, pO3, pml);
  combine_k<<<dim3(512), 256, 0, stream>>>(xT, ctx, pO2, pO3, pml, ctx);
  conv_mfma<<<dim3(512), 256, 0, stream>>>(ctx, wT2 + 3 * 589824, bo, (float*)d_out, zp);
}

// Round 16
// 248.966 us; speedup vs baseline: 1.0545x; 1.0545x over previous
//
#include <hip/hip_runtime.h>
#include <hip/hip_fp16.h>
#include <math.h>

#define NN 4096
#define CC 256

typedef __attribute__((ext_vector_type(8))) short bf16x8;
typedef __attribute__((ext_vector_type(8))) _Float16 f16x8;
typedef __attribute__((ext_vector_type(4))) float f32x4;
typedef __attribute__((ext_vector_type(16))) float f32x16;
typedef __attribute__((ext_vector_type(8))) unsigned short u16x8;
typedef __attribute__((ext_vector_type(4))) unsigned short u16x4;
typedef __attribute__((ext_vector_type(4))) unsigned int u32x4;

__device__ inline unsigned short f2bf(float f) {
  unsigned u = __float_as_uint(f);
  return (unsigned short)((u + 0x7FFFu + ((u >> 16) & 1u)) >> 16);
}
__device__ inline float bf2f(unsigned short u) {
  return __uint_as_float(((unsigned)u) << 16);
}
__device__ inline unsigned short f2h(float f) {
  __half h = __float2half(f);
  return static_cast<__half_raw>(h).x;
}

// async global->LDS, 16B per lane; dest = wave-uniform base + lane*16
__device__ inline void gload16(const void* g, void* l) {
  __builtin_amdgcn_global_load_lds(
      (const __attribute__((address_space(1))) void*)g,
      (__attribute__((address_space(3))) void*)l, 16, 0, 0);
}

// ---------------------------------------------------------------------------
// prep_k: fused input prep, grid 2048.
//   bx < 1024: w[widx] [co][ci][3][3] f32 -> wT2 [4][9][co][ci] bf16
//   bx >= 1024: x [B][C][H][W] f32 -> xT [B][N][C] bf16 (LDS transpose)
// ---------------------------------------------------------------------------
__global__ __launch_bounds__(256) void prep_k(
    const float* __restrict__ x,
    const float* __restrict__ w0, const float* __restrict__ w1,
    const float* __restrict__ w2, const float* __restrict__ w3,
    unsigned short* __restrict__ wT2, unsigned short* __restrict__ xT,
    unsigned short* __restrict__ zp)
{
  __shared__ unsigned short T[64][72];
  int bxr = blockIdx.x;
  int tid = threadIdx.x;
  if (bxr < 1024) {
    int widx = bxr >> 8;
    const float* src = (widx == 0) ? w0 : (widx == 1) ? w1
                     : (widx == 2) ? w2 : w3;
    int p = ((bxr & 255) << 8) + tid;               // p = co*256 + ci
    unsigned short* dst = wT2 + (size_t)widx * 589824;
    const float* s9 = src + (size_t)p * 9;
#pragma unroll
    for (int s = 0; s < 9; ++s) dst[(size_t)s * 65536 + p] = f2bf(s9[s]);
    if (bxr == 0 && tid < 128) zp[tid] = 0;
  } else {
    int bx = bxr - 1024;
    int b = bx >> 8, c0 = ((bx >> 6) & 3) * 64, n0 = (bx & 63) * 64;
#pragma unroll
    for (int it = 0; it < 16; ++it) {
      int c_l = (tid >> 6) + it * 4;
      int n_l = tid & 63;
      T[n_l][c_l] = f2bf(x[((size_t)(b * 256 + c0 + c_l)) * 4096 + n0 + n_l]);
    }
    __syncthreads();
#pragma unroll
    for (int it = 0; it < 8; ++it) {
      int n_l = (tid >> 5) + it * 8;
      int cp = (tid & 31) * 2;
      unsigned v = (unsigned)T[n_l][cp] | ((unsigned)T[n_l][cp + 1] << 16);
      *(unsigned*)&xT[((size_t)(b * 4096 + n0 + n_l)) * 256 + c0 + cp] = v;
    }
  }
}

// ---------------------------------------------------------------------------
// conv3x_k: the 3 QKV convs as ONE launch, grid (512, 3).  blockIdx.y picks
// weights/bias/output.  Tile 128(M) x 64(N), 9 accumulated shift-GEMMs,
// bf16 MFMA 16x16x32, XCD-swizzled blockIdx.x (512 = 8 XCD x 64).
// y=0 -> qT fp16 [B][N][C]; y=1 -> kT; y=2 -> vTc fp16 [B][C][N].
// ---------------------------------------------------------------------------
__global__ __launch_bounds__(256) void conv3x_k(
    const unsigned short* __restrict__ A,
    const unsigned short* __restrict__ wT2,     // [4][9][256][256]
    const float* __restrict__ bq, const float* __restrict__ bk,
    const float* __restrict__ bvv,
    unsigned short* __restrict__ qT, unsigned short* __restrict__ kT,
    unsigned short* __restrict__ vTc,
    const unsigned short* __restrict__ zp)
{
  __shared__ unsigned short As[2][128 * 64];   // 2 x 16KB
  __shared__ unsigned short Bs[2][64 * 64];    // 2 x 8KB

  const int by = blockIdx.y;
  const unsigned short* W = wT2 + (size_t)by * 589824;
  const float* bias = (by == 0) ? bq : (by == 1) ? bk : bvv;
  unsigned short* outp = (by == 0) ? qT : (by == 1) ? kT : vTc;
  const int mode2 = (by == 2);

  const int bx = blockIdx.x;
  const int bxs = ((bx & 7) << 6) + (bx >> 3);   // XCD-contiguous swizzle
  const int tid = threadIdx.x;
  const int lane = tid & 63;
  const int w = tid >> 6;
  const int wr = w >> 1, wc = w & 1;
  const int nt = bxs & 3;
  const int mt = bxs >> 2;
  const int m0 = mt * 128;
  const int co0 = nt * 64;

  const int aslot = (lane & 7) ^ (lane >> 3);
  int gmj[4], yj[4], xj[4];
#pragma unroll
  for (int j = 0; j < 4; ++j) {
    int row = w * 32 + j * 8 + (lane >> 3);
    int gm = m0 + row;
    gmj[j] = gm;
    int n = gm & (NN - 1);
    yj[j] = n >> 6;
    xj[j] = n & 63;
  }
  int browj[2];
#pragma unroll
  for (int j = 0; j < 2; ++j)
    browj[j] = co0 + w * 16 + j * 8 + (lane >> 3);

  f32x4 acc[4][2];
#pragma unroll
  for (int mi = 0; mi < 4; ++mi)
#pragma unroll
    for (int ni = 0; ni < 2; ++ni) acc[mi][ni] = (f32x4){0.f, 0.f, 0.f, 0.f};

  auto stage = [&](int step, int sb) {
    int s = step >> 2, t = step & 3;
    int dy = s / 3 - 1, dx = s - (s / 3) * 3 - 1;
    const unsigned short* abase = A + t * 64 + aslot * 8;
    const unsigned short* wbase = W + ((size_t)s << 16) + t * 64 + aslot * 8;
#pragma unroll
    for (int j = 0; j < 4; ++j) {
      int yy = yj[j] + dy, xx = xj[j] + dx;
      bool valid = ((unsigned)yy < 64u) && ((unsigned)xx < 64u);
      const void* ga = valid
          ? (const void*)(abase + (size_t)(gmj[j] + dy * 64 + dx) * 256)
          : (const void*)zp;
      gload16(ga, (void*)&As[sb][(w * 4 + j) * 512]);
    }
#pragma unroll
    for (int j = 0; j < 2; ++j) {
      const void* gb = (const void*)(wbase + (size_t)browj[j] * 256);
      gload16(gb, (void*)&Bs[sb][(w * 2 + j) * 512]);
    }
  };

  const int r = lane & 15;
  const int klane = lane >> 4;
  const int rs = r & 7;

  int buf = 0;
  stage(0, 0);
  __syncthreads();
  for (int step = 0; step < 36; ++step) {
    if (step + 1 < 36) stage(step + 1, buf ^ 1);
    const unsigned short* as = As[buf];
    const unsigned short* bs = Bs[buf];
#pragma unroll
    for (int kk = 0; kk < 2; ++kk) {
      int slot = (kk * 4 + klane) ^ rs;
      bf16x8 a[4], bfr[2];
#pragma unroll
      for (int mi = 0; mi < 4; ++mi)
        a[mi] = *(const bf16x8*)&as[(wr * 64 + mi * 16 + r) * 64 + slot * 8];
#pragma unroll
      for (int ni = 0; ni < 2; ++ni)
        bfr[ni] = *(const bf16x8*)&bs[(wc * 32 + ni * 16 + r) * 64 + slot * 8];
#pragma unroll
      for (int mi = 0; mi < 4; ++mi)
#pragma unroll
        for (int ni = 0; ni < 2; ++ni)
          acc[mi][ni] = __builtin_amdgcn_mfma_f32_16x16x32_bf16(
              a[mi], bfr[ni], acc[mi][ni], 0, 0, 0);
    }
    __syncthreads();
    buf ^= 1;
  }

  const int r4 = lane >> 4;
  const int colb = lane & 15;
  if (!mode2) {
#pragma unroll
    for (int ni = 0; ni < 2; ++ni) {
      int co = co0 + wc * 32 + ni * 16 + colb;
      float bv = bias[co];
#pragma unroll
      for (int mi = 0; mi < 4; ++mi) {
        int gm0 = m0 + wr * 64 + mi * 16 + r4 * 4;
#pragma unroll
        for (int rr = 0; rr < 4; ++rr) {
          float v = fmaxf(acc[mi][ni][rr] + bv, 0.f);
          outp[(size_t)(gm0 + rr) * 256 + co] = f2h(v);
        }
      }
    }
  } else {
#pragma unroll
    for (int ni = 0; ni < 2; ++ni) {
      int co = co0 + wc * 32 + ni * 16 + colb;
      float bv = bias[co];
#pragma unroll
      for (int mi = 0; mi < 4; ++mi) {
        int gm0 = m0 + wr * 64 + mi * 16 + r4 * 4;
#pragma unroll
        for (int rr = 0; rr < 4; ++rr) {
          float v = fmaxf(acc[mi][ni][rr] + bv, 0.f);
          int gm = gm0 + rr;
          int b = gm >> 12, n = gm & (NN - 1);
          outp[((size_t)(b * 256 + co)) * 4096 + n] = f2h(v);
        }
      }
    }
  }
}

// ---------------------------------------------------------------------------
// conv_mfma: final 3x3 conv, tile 128x64, XCD-swizzled; f32 [B][C][H][W] out.
// ---------------------------------------------------------------------------
__global__ __launch_bounds__(256) void conv_mfma(
    const unsigned short* __restrict__ A,
    const unsigned short* __restrict__ W,
    const float* __restrict__ bias,
    float* __restrict__ out,
    const unsigned short* __restrict__ zp)
{
  __shared__ unsigned short As[2][128 * 64];
  __shared__ unsigned short Bs[2][64 * 64];

  const int bx = blockIdx.x;
  const int bxs = ((bx & 7) << 6) + (bx >> 3);
  const int tid = threadIdx.x;
  const int lane = tid & 63;
  const int w = tid >> 6;
  const int wr = w >> 1, wc = w & 1;
  const int nt = bxs & 3;
  const int mt = bxs >> 2;
  const int m0 = mt * 128;
  const int co0 = nt * 64;

  const int aslot = (lane & 7) ^ (lane >> 3);
  int gmj[4], yj[4], xj[4];
#pragma unroll
  for (int j = 0; j < 4; ++j) {
    int row = w * 32 + j * 8 + (lane >> 3);
    int gm = m0 + row;
    gmj[j] = gm;
    int n = gm & (NN - 1);
    yj[j] = n >> 6;
    xj[j] = n & 63;
  }
  int browj[2];
#pragma unroll
  for (int j = 0; j < 2; ++j)
    browj[j] = co0 + w * 16 + j * 8 + (lane >> 3);

  f32x4 acc[4][2];
#pragma unroll
  for (int mi = 0; mi < 4; ++mi)
#pragma unroll
    for (int ni = 0; ni < 2; ++ni) acc[mi][ni] = (f32x4){0.f, 0.f, 0.f, 0.f};

  auto stage = [&](int step, int sb) {
    int s = step >> 2, t = step & 3;
    int dy = s / 3 - 1, dx = s - (s / 3) * 3 - 1;
    const unsigned short* abase = A + t * 64 + aslot * 8;
    const unsigned short* wbase = W + ((size_t)s << 16) + t * 64 + aslot * 8;
#pragma unroll
    for (int j = 0; j < 4; ++j) {
      int yy = yj[j] + dy, xx = xj[j] + dx;
      bool valid = ((unsigned)yy < 64u) && ((unsigned)xx < 64u);
      const void* ga = valid
          ? (const void*)(abase + (size_t)(gmj[j] + dy * 64 + dx) * 256)
          : (const void*)zp;
      gload16(ga, (void*)&As[sb][(w * 4 + j) * 512]);
    }
#pragma unroll
    for (int j = 0; j < 2; ++j) {
      const void* gb = (const void*)(wbase + (size_t)browj[j] * 256);
      gload16(gb, (void*)&Bs[sb][(w * 2 + j) * 512]);
    }
  };

  const int r = lane & 15;
  const int klane = lane >> 4;
  const int rs = r & 7;

  int buf = 0;
  stage(0, 0);
  __syncthreads();
  for (int step = 0; step < 36; ++step) {
    if (step + 1 < 36) stage(step + 1, buf ^ 1);
    const unsigned short* as = As[buf];
    const unsigned short* bs = Bs[buf];
#pragma unroll
    for (int kk = 0; kk < 2; ++kk) {
      int slot = (kk * 4 + klane) ^ rs;
      bf16x8 a[4], bfr[2];
#pragma unroll
      for (int mi = 0; mi < 4; ++mi)
        a[mi] = *(const bf16x8*)&as[(wr * 64 + mi * 16 + r) * 64 + slot * 8];
#pragma unroll
      for (int ni = 0; ni < 2; ++ni)
        bfr[ni] = *(const bf16x8*)&bs[(wc * 32 + ni * 16 + r) * 64 + slot * 8];
#pragma unroll
      for (int mi = 0; mi < 4; ++mi)
#pragma unroll
        for (int ni = 0; ni < 2; ++ni)
          acc[mi][ni] = __builtin_amdgcn_mfma_f32_16x16x32_bf16(
              a[mi], bfr[ni], acc[mi][ni], 0, 0, 0);
    }
    __syncthreads();
    buf ^= 1;
  }

  const int r4 = lane >> 4;
  const int colb = lane & 15;
#pragma unroll
  for (int ni = 0; ni < 2; ++ni) {
    int co = co0 + wc * 32 + ni * 16 + colb;
    float bv = bias[co];
#pragma unroll
    for (int mi = 0; mi < 4; ++mi) {
      int gm0 = m0 + wr * 64 + mi * 16 + r4 * 4;
#pragma unroll
      for (int rr = 0; rr < 4; ++rr) {
        float v = fmaxf(acc[mi][ni][rr] + bv, 0.f);
        int gm = gm0 + rr;
        int b = gm >> 12, n = gm & (NN - 1);
        out[((size_t)(b * 256 + co)) * 4096 + n] = v;
      }
    }
  }
}

// ---------------------------------------------------------------------------
// MFMA flash attention (r13-verified): QBLK=64, 4 waves, 2-way key split
// (grid 512), 48KB LDS (K double-buffered 2x16KB, V single-buffered 16KB),
// 2 __syncthreads per chunk, (256,2) -> 108 VGPR no spill, defer-rescale,
// setprio, bijective XCD swizzle.  NOTE: occupancy is register-CLASS capped
// at 2 blocks/CU (arch+acc ~172 regs -> 256-class -> 2 waves/SIMD); LDS
// shrink / grid supply / reg-staging all verified NOT to move it (r13-r15).
// Emits unnormalized partial O^T (bf16) + (m, l) per query.
// ---------------------------------------------------------------------------
__global__ __launch_bounds__(256, 2) void attn_k(
    const unsigned short* __restrict__ qT, const unsigned short* __restrict__ kT,
    const unsigned short* __restrict__ vTc,
    unsigned short* __restrict__ pO, float2* __restrict__ pml)
{
  __shared__ unsigned short Ks[2][32 * 256];   // 2 x 16KB, [key][c], swizzled
  __shared__ unsigned short Vts[256 * 32];     // 16KB, [c][key], swizzled

  const int tid = threadIdx.x;
  const int lane = tid & 63;
  const int w = tid >> 6;
  const int wq = w >> 1, wc = w & 1;
  const int hi = lane >> 5;
  const int la = lane & 31;
  const int a7 = la & 7;
  const int bx = blockIdx.x;
  const int bxs = ((bx & 7) << 6) + (bx >> 3);   // XCD n owns one (half,b)
  const int half = bxs >> 8;
  const int b = (bxs >> 6) & 3;
  const int q0 = (bxs & 63) << 6;
  const int kbase = half << 11;

  // ---- Q as B-fragments: qf[ks] = Q[q0+32wq+la][16ks+8hi .. +8] ----
  f16x8 qf[16];
  {
    const unsigned short* qp =
        qT + ((size_t)(b * NN) + q0 + 32 * wq + la) * CC + 8 * hi;
#pragma unroll
    for (int ks = 0; ks < 16; ++ks)
      qf[ks] = *(const f16x8*)(qp + ks * 16);
  }

  const unsigned short* kTb = kT + (size_t)b * NN * CC;
  const unsigned short* vTb = vTc + (size_t)b * CC * NN;

  auto stageK = [&](int t, int sb) {
    int k0 = kbase + (t << 5);
    int row_l = lane >> 5;
    int slot = lane & 31;
#pragma unroll
    for (int i = 0; i < 4; ++i) {
      int row = 8 * w + i * 2 + row_l;
      const void* src = (const void*)(kTb + (size_t)(k0 + row) * CC +
                                      ((slot ^ (row & 7)) << 3));
      gload16(src, (void*)&Ks[sb][(8 * w + i * 2) * 256]);
    }
  };
  auto stageV = [&](int t) {
    int k0 = kbase + (t << 5);
    int c_l = lane >> 2;
    int sp = lane & 3;
#pragma unroll
    for (int i = 0; i < 4; ++i) {
      int c = 64 * w + 16 * i + c_l;
      const void* src = (const void*)(vTb + (size_t)c * NN + k0 +
                                      ((sp ^ ((c >> 2) & 3)) << 3));
      gload16(src, (void*)&Vts[(64 * w + 16 * i) * 32]);
    }
  };

  float mprev = -INFINITY, lsum = 0.f;
  f32x16 O[4];
#pragma unroll
  for (int nc = 0; nc < 4; ++nc)
#pragma unroll
    for (int rr = 0; rr < 16; ++rr) O[nc][rr] = 0.f;

  stageK(0, 0);
  __syncthreads();

  for (int t = 0; t < 64; ++t) {
    const int cur = t & 1;
    stageV(t);
    if (t + 1 < 64) stageK(t + 1, cur ^ 1);

    // ---- QK^T (swapped): S^T[32 keys][32 q] ----
    f32x16 S0;
#pragma unroll
    for (int rr = 0; rr < 16; ++rr) S0[rr] = 0.f;
    const unsigned short* ks_ = Ks[cur];
    __builtin_amdgcn_s_setprio(1);
#pragma unroll
    for (int ks = 0; ks < 16; ++ks) {
      f16x8 a0 = *(const f16x8*)&ks_[la * 256 + ((((ks << 1) + hi) ^ a7) << 3)];
      S0 = __builtin_amdgcn_mfma_f32_32x32x16_f16(a0, qf[ks], S0, 0, 0, 0);
    }
    __builtin_amdgcn_s_setprio(0);

    // ---- online softmax, defer-rescale (THR=8) ----
    float mloc = S0[0];
#pragma unroll
    for (int rr = 1; rr < 16; ++rr) mloc = fmaxf(mloc, S0[rr]);
    {
      auto sw = __builtin_amdgcn_permlane32_swap(
          __float_as_uint(mloc), __float_as_uint(mloc), false, false);
      mloc = fmaxf(__uint_as_float(sw[0]), __uint_as_float(sw[1]));
    }
    if (!__all(mloc <= mprev + 8.f)) {
      float mnew = fmaxf(mprev, mloc);
      float sc = __expf(mprev - mnew);   // exp(-inf)=0 on first chunk
      lsum *= sc;
#pragma unroll
      for (int nc = 0; nc < 4; ++nc)
#pragma unroll
        for (int rr = 0; rr < 16; ++rr) O[nc][rr] *= sc;
      mprev = mnew;
    }
    float rsm = 0.f;
#pragma unroll
    for (int rr = 0; rr < 16; ++rr) {
      S0[rr] = __expf(S0[rr] - mprev);
      rsm += S0[rr];
    }
    {
      auto sw = __builtin_amdgcn_permlane32_swap(
          __float_as_uint(rsm), __float_as_uint(rsm), false, false);
      rsm = __uint_as_float(sw[0]) + __uint_as_float(sw[1]);
    }
    lsum += rsm;

    // ---- pack P to fp16 A-row-fragments (cvt_pkrtz + permlane32_swap) ----
    f16x8 pf[2];
#pragma unroll
    for (int kk = 0; kk < 2; ++kk) {
      const int r0 = kk * 8;
      unsigned w0 = __builtin_bit_cast(unsigned,
          __builtin_amdgcn_cvt_pkrtz(S0[r0 + 0], S0[r0 + 1]));
      unsigned w1 = __builtin_bit_cast(unsigned,
          __builtin_amdgcn_cvt_pkrtz(S0[r0 + 2], S0[r0 + 3]));
      unsigned w2 = __builtin_bit_cast(unsigned,
          __builtin_amdgcn_cvt_pkrtz(S0[r0 + 4], S0[r0 + 5]));
      unsigned w3 = __builtin_bit_cast(unsigned,
          __builtin_amdgcn_cvt_pkrtz(S0[r0 + 6], S0[r0 + 7]));
      auto sA = __builtin_amdgcn_permlane32_swap(w0, w2, false, false);
      auto sB = __builtin_amdgcn_permlane32_swap(w1, w3, false, false);
      u32x4 fw;
      fw[0] = sA[0]; fw[1] = sB[0]; fw[2] = sA[1]; fw[3] = sB[1];
      pf[kk] = __builtin_bit_cast(f16x8, fw);
    }

    __syncthreads();   // beta: V(t) landed (drains vmcnt for all waves)

    // ---- PV: O^T[c][q] += Vt-frag x P-frag ----
    __builtin_amdgcn_s_setprio(1);
#pragma unroll
    for (int kk = 0; kk < 2; ++kk) {
#pragma unroll
      for (int nc = 0; nc < 4; ++nc) {
        int c = 128 * wc + 32 * nc + la;
        f16x8 vf = *(const f16x8*)&Vts[c * 32 +
                                       ((((kk << 1) + hi) ^ ((c >> 2) & 3)) << 3)];
        O[nc] = __builtin_amdgcn_mfma_f32_32x32x16_f16(vf, pf[kk], O[nc], 0, 0, 0);
      }
    }
    __builtin_amdgcn_s_setprio(0);

    __syncthreads();   // alpha: PV done -> Vts / Ks[cur] free for next iter
  }

  // ---- epilogue: unnormalized partial O^T (bf16) + (m,l) ----
  {
    int n = q0 + 32 * wq + la;
    unsigned short* dst = pO + (((size_t)(half * 4 + b)) * NN + n) * CC;
#pragma unroll
    for (int nc = 0; nc < 4; ++nc) {
#pragma unroll
      for (int tq = 0; tq < 4; ++tq) {
        int c0 = 128 * wc + 32 * nc + 8 * tq + 4 * hi;
        u16x4 pk;
        pk[0] = f2bf(O[nc][4 * tq + 0]);
        pk[1] = f2bf(O[nc][4 * tq + 1]);
        pk[2] = f2bf(O[nc][4 * tq + 2]);
        pk[3] = f2bf(O[nc][4 * tq + 3]);
        *(u16x4*)&dst[c0] = pk;
      }
    }
    if (wc == 0 && hi == 0)
      pml[(size_t)half * 4 * NN + (size_t)b * NN + n] =
          make_float2(mprev, lsum);
  }
}

// ---------------------------------------------------------------------------
// combine_k: merge the two key-half partials -> ctx bf16 [B][N][C] (x2).
// ---------------------------------------------------------------------------
__global__ __launch_bounds__(256) void combine_k(
    const unsigned short* __restrict__ pO, const float2* __restrict__ pml,
    unsigned short* __restrict__ ctx)
{
  int bx = blockIdx.x;
  int b = bx >> 6;
  int q = ((bx & 63) << 6) + (threadIdx.x >> 2);
  int c0 = (threadIdx.x & 3) << 6;
  size_t nidx = (size_t)b * NN + q;
  float2 ml0 = pml[nidx];
  float2 ml1 = pml[(size_t)4 * NN + nidx];
  float m = fmaxf(ml0.x, ml1.x);
  float w0 = __expf(ml0.x - m), w1 = __expf(ml1.x - m);
  float inv = 2.f / (ml0.y * w0 + ml1.y * w1);
  const unsigned short* p0 = pO + nidx * CC + c0;
  const unsigned short* p1 = pO + (size_t)4 * NN * CC + nidx * CC + c0;
  unsigned short* d = ctx + nidx * CC + c0;
#pragma unroll
  for (int j = 0; j < 8; ++j) {
    u16x8 a = *(const u16x8*)(p0 + j * 8);
    u16x8 bb = *(const u16x8*)(p1 + j * 8);
    u16x8 o;
#pragma unroll
    for (int e = 0; e < 8; ++e)
      o[e] = f2bf((bf2f(a[e]) * w0 + bf2f(bb[e]) * w1) * inv);
    *(u16x8*)(d + j * 8) = o;
  }
}

extern "C" void kernel_launch(void* const* d_in, const int* in_sizes, int n_in,
                              void* d_out, int out_size, void* d_ws, size_t ws_size,
                              hipStream_t stream) {
  const float* x  = (const float*)d_in[0];
  const float* wq = (const float*)d_in[1];
  const float* bq = (const float*)d_in[2];
  const float* wk = (const float*)d_in[3];
  const float* bk = (const float*)d_in[4];
  const float* wv = (const float*)d_in[5];
  const float* bv = (const float*)d_in[6];
  const float* wo = (const float*)d_in[7];
  const float* bo = (const float*)d_in[8];

  char* ws = (char*)d_ws;
  unsigned short* xT  = (unsigned short*)(ws);              // bf16 [B][N][C]
  unsigned short* wT2 = (unsigned short*)(ws + 8388608);    // bf16 [4][9][co][ci]
  unsigned short* qT  = (unsigned short*)(ws + 13107200);   // fp16 [B][N][C]
  unsigned short* kT  = (unsigned short*)(ws + 21495808);   // fp16 [B][N][C]
  unsigned short* vTc = (unsigned short*)(ws + 29884416);   // fp16 [B][C][N]
  unsigned short* ctx = (unsigned short*)(ws + 38273024);   // bf16 [B][N][C]
  unsigned short* zp  = (unsigned short*)(ws + 46661632);   // 512 B zeros
  unsigned short* pO  = (unsigned short*)(ws + 46662144);   // bf16 [2][B][N][C] 16MB
  float2*         pml = (float2*)(ws + 63439360);           // f32x2 [2][B][N] 256KB

  prep_k<<<dim3(2048), 256, 0, stream>>>(x, wq, wk, wv, wo, wT2, xT, zp);
  conv3x_k<<<dim3(512, 3), 256, 0, stream>>>(xT, wT2, bq, bk, bv, qT, kT, vTc, zp);
  attn_k<<<dim3(512), 256, 0, stream>>>(qT, kT, vTc, pO, pml);
  combine_k<<<dim3(256), 256, 0, stream>>>(pO, pml, ctx);
  conv_mfma<<<dim3(512), 256, 0, stream>>>(ctx, wT2 + 3 * 589824, bo, (float*)d_out, zp);
}